// Round 12
// baseline (128.109 us; speedup 1.0000x reference)
//
#include <hip/hip_runtime.h>
#include <hip/hip_bf16.h>

constexpr int kN = 8192;
constexpr int kD = 128;
constexpr int BM = 32;      // rows per block in main kernel (2 MFMA row-tiles)
constexpr int BW = 32;      // j-window per iteration (= MFMA K)
constexpr int JSPLIT = 8;   // j-range strips (grid at 2048 blocks)
constexpr int LDA = 40;     // A-tile LDS row stride (80B, 16B-aligned, conflict-free)
constexpr int TB = 64;      // rowsum tile
constexpr int NB = kN / TB; // 128

typedef __bf16 v8bf __attribute__((ext_vector_type(8)));
typedef float  v4f  __attribute__((ext_vector_type(4)));

// async global->LDS, 16B per lane (r10-proven).
__device__ __forceinline__ void gload16(const void* g, void* l) {
    __builtin_amdgcn_global_load_lds(
        (const __attribute__((address_space(1))) void*)g,
        (__attribute__((address_space(3))) void*)l, 16, 0, 0);
}

// K_raw with 3 transcendentals (round-8 proven).
__device__ __forceinline__ float kraw_f(float4 ci, float sqi, float4 cj, float sqj) {
    float d2 = sqi + sqj - 2.0f * (ci.x * cj.x + ci.y * cj.y + ci.z * cj.z);
    d2 = fmaxf(d2, 1e-12f);
    float Dd = __builtin_amdgcn_sqrtf(d2);
    float a = 0.5f * (ci.w + cj.w);
    float t = a * (-0.5f * __builtin_amdgcn_logf(d2));                // -a*log2(D)
    t = fminf(fmaxf(t, -26.575424759098897f), 9.965784284662087f);   // log2(1e-8), log2(1000)
    float K = __builtin_amdgcn_exp2f(fmaf(Dd, -0.12022458674074695f, t));
    return fminf(K, 1000.0f);  // K >= 0 always
}

// --- kernel 1: pack coords+alpha into float4 (proven) ----------------------
__global__ void pack_k(const float* __restrict__ coords, const float* __restrict__ alpha,
                       float4* __restrict__ c4) {
    int j = blockIdx.x * 256 + threadIdx.x;
    if (j < kN) {
        c4[j] = make_float4(coords[3 * j], coords[3 * j + 1], coords[3 * j + 2], alpha[j]);
    }
}

// --- kernel 2: transpose latent [N][128] f32 -> latT [128][N] bf16 (proven) -
__global__ void transpose_k(const float* __restrict__ latent, __bf16* __restrict__ latT) {
    __shared__ float tile[32][33];
    int t = threadIdx.x;
    int tx = t & 31, ty = t >> 5;          // 32 x 8
    int j0 = blockIdx.x * 32, d0 = blockIdx.y * 32;
    #pragma unroll
    for (int i = 0; i < 32; i += 8)
        tile[ty + i][tx] = latent[(size_t)(j0 + ty + i) * kD + d0 + tx];
    __syncthreads();
    #pragma unroll
    for (int i = 0; i < 32; i += 8)
        latT[(size_t)(d0 + ty + i) * kN + j0 + tx] = (__bf16)tile[tx][ty + i];
}

// --- kernel 3: SYMMETRIC row sums (round-11 proven) ------------------------
__global__ __launch_bounds__(256) void rowsum_sym_k(const float4* __restrict__ c4,
                                                    float* __restrict__ rsum) {
    __shared__ float4 rc4[TB];
    __shared__ float  rsq[TB];
    __shared__ float  rowbuf[TB][TB + 1];   // 16.25 KB

    // decode triangular pair (bi <= bj) from linear block index
    int L = blockIdx.x;
    int bi = (int)((2 * NB + 1 - sqrtf((float)((2 * NB + 1) * (2 * NB + 1) - 8 * L))) * 0.5f);
    #pragma unroll
    for (int f = 0; f < 2; ++f) {
        int s0 = bi * NB - bi * (bi - 1) / 2;
        int s1 = (bi + 1) * NB - (bi + 1) * bi / 2;
        if (L >= s1) ++bi;
        else if (L < s0) --bi;
    }
    int sbi = bi * NB - bi * (bi - 1) / 2;
    int bj = bi + (L - sbi);
    bool diag = (bi == bj);

    const int t = threadIdx.x;
    const int l = t & 63;
    const int w = t >> 6;

    if (t < TB) {
        float4 ci = c4[bi * TB + t];
        rc4[t] = ci;
        rsq[t] = ci.x * ci.x + ci.y * ci.y + ci.z * ci.z;
    }
    __syncthreads();

    float4 cj = c4[bj * TB + l];
    float sqj = cj.x * cj.x + cj.y * cj.y + cj.z * cj.z;

    float colacc = 0.f;
    #pragma unroll
    for (int rr = 0; rr < 16; ++rr) {
        int r = w * 16 + rr;
        float k = kraw_f(rc4[r], rsq[r], cj, sqj);
        if (diag && r == l) k = 0.f;
        colacc += k;
        rowbuf[r][l] = k;
    }
    __syncthreads();

    // row sums: thread t -> row r = t>>2, quarter q = t&3 (adjacent lanes)
    {
        int r = t >> 2, q = t & 3;
        float p = 0.f;
        #pragma unroll
        for (int m = 0; m < 16; ++m) p += rowbuf[r][q * 16 + m];
        p += __shfl_xor(p, 1, 64);
        p += __shfl_xor(p, 2, 64);
        if (q == 0) atomicAdd(&rsum[bi * TB + r], p);
    }
    if (!diag) atomicAdd(&rsum[bj * TB + l], colacc);
}

// --- kernel 4: fused K write + MFMA GEMM — full dbuf, ONE barrier/iter -----
// Window = 32 cols (= MFMA K). Iter cb: prepare window cb+1 (async B staging
// into Blin[p^1], kraw -> Kout + Alds[p^1]) while doing MFMA on window cb
// from [p]; single barrier. Staging latency spans a full iteration. Linear
// [128][32] B layout is inherently bank-conflict-free for b128 frag reads.
__global__ __launch_bounds__(256, 2) void main_k(
    const float4* __restrict__ c4, const float* __restrict__ rsum,
    const __bf16* __restrict__ latT, float* __restrict__ outp, float* __restrict__ Kout) {

    __shared__ __bf16 Blin[2][kD][BW];  // 16 KB
    __shared__ __bf16 Alds[2][BM][LDA]; // 5 KB
    __shared__ float4 c4row[BM];
    __shared__ float  sqrow[BM];
    __shared__ float  invrow[BM];

    const int t = threadIdx.x;
    const int lane = t & 63;
    const int wave = t >> 6;
    const int i0 = blockIdx.x * BM;
    const int jstrip = blockIdx.y * (kN / JSPLIT);
    constexpr int NIT = (kN / JSPLIT) / BW;   // 32

    if (t < BM) {
        float4 ci = c4[i0 + t];
        c4row[t] = ci;
        sqrow[t] = ci.x * ci.x + ci.y * ci.y + ci.z * ci.z;
        invrow[t] = 1.0f / (rsum[i0 + t] + 1e-8f);
    }
    __syncthreads();

    // kraw mapping: col-pair c2 = t&15 -> cols {2c2, 2c2+1}; rows rb, rb+1
    const int c2 = t & 15;
    const int rb = (t >> 4) * 2;
    float4 rc[2]; float rs[2], rv[2];
    #pragma unroll
    for (int rr = 0; rr < 2; ++rr) {
        rc[rr] = c4row[rb + rr];
        rs[rr] = sqrow[rb + rr];
        rv[rr] = invrow[rb + rr];
    }

    // MFMA fragment addressing (proven mapping): A row = lane&15, k-slot =
    // lane>>4 (8 elems); B dim = dbase + {0,16} + lane&15, same k-slot.
    const int arow = lane & 15;
    const int slot = lane >> 4;
    const int dbase = wave * 32;

    // staging mapping (linear, no swizzle): round it: dest = it*4096 + t*16
    // -> row = it*64 + (t>>2), col-slot = t&3
    const int srow = t >> 2;
    const int scol = (t & 3) * 16;   // bytes

    v4f acc[2][2];
    #pragma unroll
    for (int rt = 0; rt < 2; ++rt)
        #pragma unroll
        for (int dt = 0; dt < 2; ++dt) acc[rt][dt] = (v4f){0.f, 0.f, 0.f, 0.f};

    // ---- prepare window W into buffers [pb] (staging + kraw + Kout) ----
    auto prepare = [&](int W, int pb) {
        const int j0 = jstrip + W * BW;
        #pragma unroll
        for (int it = 0; it < 2; ++it) {
            int row = it * 64 + srow;
            const char* src = (const char*)latT + ((size_t)row * kN + j0) * 2 + scol;
            char* dst = (char*)&Blin[pb][0][0] + it * 4096 + t * 16;
            gload16(src, dst);
        }
        const int gjA = j0 + 2 * c2, gjB = gjA + 1;
        const float4 cjA = c4[gjA];
        const float4 cjB = c4[gjB];
        const float sqA = cjA.x * cjA.x + cjA.y * cjA.y + cjA.z * cjA.z;
        const float sqB = cjB.x * cjB.x + cjB.y * cjB.y + cjB.z * cjB.z;
        #pragma unroll
        for (int rr = 0; rr < 2; ++rr) {
            int gi = i0 + rb + rr;
            float kA = (gi == gjA) ? 0.0f : kraw_f(rc[rr], rs[rr], cjA, sqA);
            float kB = (gi == gjB) ? 0.0f : kraw_f(rc[rr], rs[rr], cjB, sqB);
            float knA = kA * rv[rr];
            float knB = kB * rv[rr];
            float2 st = {knA, knB};
            *reinterpret_cast<float2*>(Kout + (size_t)gi * kN + gjA) = st;
            __bf16 hA = (__bf16)knA, hB = (__bf16)knB;
            unsigned pk = ((unsigned)*(unsigned short*)&hB << 16) | *(unsigned short*)&hA;
            *reinterpret_cast<unsigned*>(&Alds[pb][rb + rr][2 * c2]) = pk;
        }
    };

    prepare(0, 0);
    __syncthreads();

    for (int cb = 0; cb < NIT; ++cb) {
        const int p = cb & 1;
        if (cb + 1 < NIT) prepare(cb + 1, p ^ 1);

        // MFMA on window cb from buffers [p]
        v8bf a0 = *reinterpret_cast<const v8bf*>(&Alds[p][arow][slot * 8]);
        v8bf a1 = *reinterpret_cast<const v8bf*>(&Alds[p][16 + arow][slot * 8]);
        v8bf b0 = *reinterpret_cast<const v8bf*>(&Blin[p][dbase + arow][slot * 8]);
        v8bf b1 = *reinterpret_cast<const v8bf*>(&Blin[p][dbase + 16 + arow][slot * 8]);
        acc[0][0] = __builtin_amdgcn_mfma_f32_16x16x32_bf16(a0, b0, acc[0][0], 0, 0, 0);
        acc[0][1] = __builtin_amdgcn_mfma_f32_16x16x32_bf16(a0, b1, acc[0][1], 0, 0, 0);
        acc[1][0] = __builtin_amdgcn_mfma_f32_16x16x32_bf16(a1, b0, acc[1][0], 0, 0, 0);
        acc[1][1] = __builtin_amdgcn_mfma_f32_16x16x32_bf16(a1, b1, acc[1][1], 0, 0, 0);

        __syncthreads();
    }

    // epilogue: D frag col = lane&15 (dim), row = (lane>>4)*4 + q  [m89 proven]
    const int row = (lane >> 4) * 4;
    const int col0 = wave * 32 + (lane & 15);
    #pragma unroll
    for (int rt = 0; rt < 2; ++rt)
        #pragma unroll
        for (int dt = 0; dt < 2; ++dt)
            #pragma unroll
            for (int q = 0; q < 4; ++q)
                atomicAdd(&outp[(size_t)(i0 + rt * 16 + row + q) * kD + col0 + dt * 16],
                          acc[rt][dt][q]);
}

extern "C" void kernel_launch(void* const* d_in, const int* in_sizes, int n_in,
                              void* d_out, int out_size, void* d_ws, size_t ws_size,
                              hipStream_t stream) {
    const float* latent = (const float*)d_in[0];
    const float* coords = (const float*)d_in[1];
    const float* alpha  = (const float*)d_in[2];

    float* outp = (float*)d_out;                    // [8192][128]
    float* Kout = (float*)d_out + (size_t)kN * kD;  // [8192][8192]

    // ws layout: byte-identical to the proven footprint.
    char* ws = (char*)d_ws;
    __bf16* latT = (__bf16*)ws;                                   // 2 MiB
    float4* c4   = (float4*)(ws + 2u * 1024 * 1024);              // 128 KiB
    float*  rsum = (float*)(ws + 2u * 1024 * 1024 + 128 * 1024);  // 32 KiB

    hipMemsetAsync(outp, 0, (size_t)kN * kD * sizeof(float), stream);
    hipMemsetAsync(rsum, 0, kN * sizeof(float), stream);

    pack_k<<<dim3(kN / 256), dim3(256), 0, stream>>>(coords, alpha, c4);
    transpose_k<<<dim3(kN / 32, kD / 32), dim3(256), 0, stream>>>(latent, latT);
    rowsum_sym_k<<<dim3(NB * (NB + 1) / 2), dim3(256), 0, stream>>>(c4, rsum);
    main_k<<<dim3(kN / BM, JSPLIT), dim3(256), 0, stream>>>(c4, rsum, latT, outp, Kout);
}